// Round 5
// baseline (313.036 us; speedup 1.0000x reference)
//
#include <hip/hip_runtime.h>

#define KTAPS 9
#define DIL 6
#define BN_EPS 1e-5f
#define BB 8
#define CIN 256
#define COUT 256
#define NPTS 8192
#define BN 64
#define XOFF 32      // window col 0 = n0 - XOFF; 128 window cols (halo 32/32 >= 24)
#define BSTRIDE 40   // B row stride in shorts (80 B; 16B-aligned granules)

typedef __attribute__((ext_vector_type(8))) short short8;
typedef __attribute__((ext_vector_type(4))) float f32x4;

__device__ __forceinline__ unsigned short f2bf(float f) {
  union { float f; unsigned u; } v; v.f = f;
  unsigned r = v.u + 0x7fffu + ((v.u >> 16) & 1u);   // RNE
  return (unsigned short)(r >> 16);
}

__device__ __forceinline__ void async16(const void* gp, void* lp) {
  __builtin_amdgcn_global_load_lds(
      (const __attribute__((address_space(1))) unsigned int*)gp,
      (__attribute__((address_space(3))) unsigned int*)lp, 16, 0, 0);
}

// ---------------------------------------------------------------- pre: pack W + zero sums
// Wa[chunk][mi][kk]; chunk = ktap*8 + c8; element = W[mi][c8*32+kk][ktap]
__global__ __launch_bounds__(256)
void pre_kernel(const float* __restrict__ W, short* __restrict__ Wa,
                float* __restrict__ sums) {
  int bid = blockIdx.x;
  if (bid < 2304) {
    int idx = bid * 256 + threadIdx.x;
    int kk = idx & 31;
    int mi = (idx >> 5) & 255;
    int chunk = idx >> 13;
    int ktap = chunk >> 3;
    int c = ((chunk & 7) << 5) + kk;
    Wa[idx] = (short)f2bf(W[(size_t)mi * (CIN * KTAPS) + c * KTAPS + ktap]);
  } else {
    if (threadIdx.x < 512) sums[threadIdx.x] = 0.f;
  }
}

// ---------------------------------------------------------------- MFMA conv
// BN=64, 3 blocks/CU. Per-tap pipeline (build k+1 || MFMA k); A regs dbuf from
// L2-resident Wa; x staged by global_load_lds into chunked [q][ch][c] layout
// (DMA lane order == layout); OOB handled by address clamp (x*g with g=0).
// lgkm-only barriers per tap; one vmcnt-drain barrier per c8 (x dbuf publish).
__global__ __launch_bounds__(256, 3)
void conv_mfma(const float* __restrict__ x, const float* __restrict__ coords,
               const float* __restrict__ rot, const float* __restrict__ dist,
               const short* __restrict__ Wa, const float* __restrict__ bias,
               float* __restrict__ out,
               float* __restrict__ sums1, float* __restrict__ sums2) {
  __shared__ float x_win[2][4][32][32];       // 32 KB  x window dbuf, chunked
  __shared__ short B_lds[2][BN][BSTRIDE];     // 10 KB  per-tap B dbuf (swizzled granules)
  __shared__ float g_lds[KTAPS][BN];          // 2.25 KB tap weights

  const int tid = threadIdx.x;
  const int b = blockIdx.y;
  const int n0 = blockIdx.x * BN;
  const int wave = tid >> 6;
  const int lane = tid & 63;
  const int col = lane & 15;
  const int quad = lane >> 4;

  // ---- tap weights -> g_lds (wave w covers taps w, w+4, w+8 for point lane)
  {
    const float* cb = coords + (size_t)b * 3 * NPTS;
    const float* rb = rot + (size_t)b * 3 * NPTS;
    const float* db = dist + (size_t)b * NPTS;
    const int n = n0 + lane;
    float c0x = cb[n], c0y = cb[NPTS + n], c0z = cb[2 * NPTS + n];
    float r0x = rb[n], r0y = rb[NPTS + n], r0z = rb[2 * NPTS + n];
    float d0 = db[n];
    float r0n = r0x * r0x + r0y * r0y + r0z * r0z;
    for (int k = wave; k < KTAPS; k += 4) {
      int j = n + (k - KTAPS / 2) * DIL;
      float gv = 0.f;
      if (j >= 0 && j < NPTS) {
        float dcx = c0x - cb[j], dcy = c0y - cb[NPTS + j], dcz = c0z - cb[2 * NPTS + j];
        float dc = dcx * dcx + dcy * dcy + dcz * dcz;
        float dd = d0 - db[j];
        dd *= dd;
        float gauss = expf(-(dc + dd) * 0.5f);
        float rjx = rb[j], rjy = rb[NPTS + j], rjz = rb[2 * NPTS + j];
        float num = r0x * rjx + r0y * rjy + r0z * rjz;
        float den = sqrtf(r0n * (rjx * rjx + rjy * rjy + rjz * rjz)) + 1e-8f;
        gv = gauss * fabsf(num / den);
      }
      g_lds[k][lane] = gv;
    }
  }

  const float* xb = x + (size_t)b * CIN * NPTS;
  const int arow0 = (wave * 64 + col) * 32 + quad * 8;  // short offset in a Wa chunk
  // B write addr (shorts): row = lane, granule = wave, 16B-granule XOR swizzle
  const int wrB = lane * BSTRIDE + ((wave ^ ((lane >> 3) & 3)) << 3);

  short8 af[2][4];                  // A double buffer

#define LOADAF(AF, CHUNK)                                               \
  {                                                                     \
    const short* p_ = Wa + (size_t)(CHUNK) * 8192 + arow0;              \
    _Pragma("unroll")                                                   \
    for (int m = 0; m < 4; ++m) AF[m] = *(const short8*)(p_ + m * 512); \
  }

  // DMA x window for channel-octet C8N into buf (C8N)&1; wave handles its own
  // 8-channel granule, 4 col-chunks. Per-lane clamped global src, lane-linear LDS.
#define STAGE_DMA(C8N)                                                  \
  {                                                                     \
    const int buf_ = (C8N)&1;                                           \
    const int ch_ = wave * 8 + (lane >> 3);                             \
    const float* gr_ = xb + (size_t)((C8N)*32 + ch_) * NPTS;            \
    const int cg_ = (lane & 7) * 4;                                     \
    _Pragma("unroll")                                                   \
    for (int q_ = 0; q_ < 4; ++q_) {                                    \
      int jg_ = n0 - XOFF + q_ * 32 + cg_;                              \
      jg_ = jg_ < 0 ? 0 : (jg_ > NPTS - 4 ? NPTS - 4 : jg_);            \
      async16(gr_ + jg_, (float*)&x_win[buf_][q_][wave * 8][0] + lane * 4); \
    }                                                                   \
  }

  // build B for tap K into buf P from x buf XC: thread = (row=lane, granule=wave)
#define BUILD(K, P, XC)                                                 \
  {                                                                     \
    float g_ = g_lds[K][lane];                                          \
    const int w_ = lane + ((K)-KTAPS / 2) * DIL + XOFF;                 \
    const float* xp_ = &x_win[XC][0][0][0] + ((w_ >> 5) << 10) + (w_ & 31) + wave * 256; \
    short8 p_;                                                          \
    _Pragma("unroll")                                                   \
    for (int cc = 0; cc < 8; ++cc)                                      \
      p_[cc] = (short)f2bf(xp_[cc * 32] * g_);                          \
    *(short8*)(&B_lds[P][0][0] + wrB) = p_;                             \
  }

#define MFMA_TAP(P, AF)                                                 \
  {                                                                     \
    const short* bb_ = &B_lds[P][0][0];                                 \
    _Pragma("unroll")                                                   \
    for (int j = 0; j < 4; ++j) {                                       \
      short8 bfv_ = *(const short8*)(bb_ + (j * 16 + col) * BSTRIDE +   \
                                     ((quad ^ ((2 * j + (col >> 3)) & 3)) << 3)); \
      _Pragma("unroll")                                                 \
      for (int m = 0; m < 4; ++m)                                       \
        acc[m][j] = __builtin_amdgcn_mfma_f32_16x16x32_bf16(AF[m], bfv_, acc[m][j], 0, 0, 0); \
    }                                                                   \
  }

// pure-LDS barrier: no vmcnt drain (DMA + A loads stay in flight)
#define BAR()                                                           \
  {                                                                     \
    asm volatile("s_waitcnt lgkmcnt(0)" ::: "memory");                  \
    __builtin_amdgcn_s_barrier();                                       \
    __builtin_amdgcn_sched_barrier(0);                                  \
  }

// full barrier: drains DMA so all waves may read the new x buffer
#define BARFULL()                                                       \
  {                                                                     \
    asm volatile("s_waitcnt vmcnt(0) lgkmcnt(0)" ::: "memory");         \
    __builtin_amdgcn_s_barrier();                                       \
    __builtin_amdgcn_sched_barrier(0);                                  \
  }

// taps 0..7: prefetch A(k+1), build B(k+1), MFMA(k)
#define TAPX(K, C8)                                                     \
  {                                                                     \
    LOADAF(af[((K) + 1 + ((C8)&1)) & 1], 8 * ((K) + 1) + (C8));         \
    BUILD((K) + 1, ((C8) + (K) + 1) & 1, (C8)&1);                       \
    MFMA_TAP(((C8) + (K)) & 1, af[((K) + ((C8)&1)) & 1]);               \
    BAR();                                                              \
  }

#define C8BODY(C8, DN)                                                  \
  {                                                                     \
    if (DN) STAGE_DMA((C8) + 1);                                        \
    TAPX(0, C8)                                                         \
    TAPX(1, C8)                                                         \
    TAPX(2, C8)                                                         \
    TAPX(3, C8)                                                         \
    TAPX(4, C8)                                                         \
    TAPX(5, C8)                                                         \
    TAPX(6, C8)                                                         \
    TAPX(7, C8)                                                         \
    /* tap 8: publish new x buf, build B[0] of next c8, MFMA(8) */      \
    BARFULL();                                                          \
    if (DN) {                                                           \
      LOADAF(af[((C8) + 1) & 1], (C8) + 1);                             \
      BUILD(0, ((C8) + 1) & 1, ((C8) + 1) & 1);                         \
    }                                                                   \
    MFMA_TAP((C8)&1, af[(C8)&1]);                                       \
    BAR();                                                              \
  }

  f32x4 acc[4][4];
#pragma unroll
  for (int m = 0; m < 4; ++m)
#pragma unroll
    for (int j = 0; j < 4; ++j) acc[m][j] = (f32x4)0.f;

  // ---- prologue: DMA x_win[0], preload A chunk 0, publish, build B[0]
  STAGE_DMA(0);
  LOADAF(af[0], 0);
  asm volatile("s_waitcnt vmcnt(0)" ::: "memory");
  __syncthreads();          // x_win[0] + g_lds published
  BUILD(0, 0, 0);           // B[0] of c8=0 -> buf 0
  __syncthreads();          // B[0] published

#pragma unroll 1
  for (int c2 = 0; c2 < 4; ++c2) {
    const int c8a = 2 * c2;
    const int c8b = 2 * c2 + 1;
    const bool dnb = (c2 < 3);
    C8BODY(c8a, true);
    C8BODY(c8b, dnb);
  }

  // ---- epilogue: bias, BN partial sums, store
  const int obase = wave * 64;
  float* outp = out + (size_t)b * COUT * NPTS + n0;
#pragma unroll
  for (int m = 0; m < 4; ++m) {
    const int o0 = obase + m * 16 + quad * 4;
    const float4 bv = *(const float4*)&bias[o0];
#pragma unroll
    for (int j = 0; j < 4; ++j) {
      acc[m][j][0] += bv.x; acc[m][j][1] += bv.y;
      acc[m][j][2] += bv.z; acc[m][j][3] += bv.w;
    }
#pragma unroll
    for (int r = 0; r < 4; ++r) {
      float s1 = 0.f, s2 = 0.f;
#pragma unroll
      for (int j = 0; j < 4; ++j) {
        float v = acc[m][j][r];
        s1 += v; s2 += v * v;
      }
      s1 += __shfl_xor(s1, 1); s2 += __shfl_xor(s2, 1);
      s1 += __shfl_xor(s1, 2); s2 += __shfl_xor(s2, 2);
      s1 += __shfl_xor(s1, 4); s2 += __shfl_xor(s2, 4);
      s1 += __shfl_xor(s1, 8); s2 += __shfl_xor(s2, 8);
      if (col == 0) {
        atomicAdd(&sums1[o0 + r], s1);
        atomicAdd(&sums2[o0 + r], s2);
      }
#pragma unroll
      for (int j = 0; j < 4; ++j)
        outp[(size_t)(o0 + r) * NPTS + j * 16 + col] = acc[m][j][r];
    }
  }
}

// ---------------------------------------------------------------- BN + ReLU
__global__ __launch_bounds__(256)
void bn_apply(float* __restrict__ out, const float* __restrict__ sums1,
              const float* __restrict__ sums2, const float* __restrict__ gamma,
              const float* __restrict__ beta) {
  int bo = blockIdx.x;
  int o = bo & (COUT - 1);
  const float inv = 1.f / (float)(BB * NPTS);
  float mean = sums1[o] * inv;
  float var = sums2[o] * inv - mean * mean;
  float scale = gamma[o] * rsqrtf(var + BN_EPS);
  float shift = beta[o] - mean * scale;
  float4* p = (float4*)(out + (size_t)bo * NPTS);
  for (int i = threadIdx.x; i < NPTS / 4; i += blockDim.x) {
    float4 v = p[i];
    v.x = fmaxf(fmaf(v.x, scale, shift), 0.f);
    v.y = fmaxf(fmaf(v.y, scale, shift), 0.f);
    v.z = fmaxf(fmaf(v.z, scale, shift), 0.f);
    v.w = fmaxf(fmaf(v.w, scale, shift), 0.f);
    p[i] = v;
  }
}

// ---------------------------------------------------------------- launch
extern "C" void kernel_launch(void* const* d_in, const int* in_sizes, int n_in,
                              void* d_out, int out_size, void* d_ws, size_t ws_size,
                              hipStream_t stream) {
  const float* x      = (const float*)d_in[0];
  const float* coords = (const float*)d_in[1];
  const float* rot    = (const float*)d_in[2];
  const float* dist   = (const float*)d_in[3];
  const float* W      = (const float*)d_in[4];
  const float* bias   = (const float*)d_in[5];
  const float* gamma  = (const float*)d_in[6];
  const float* beta   = (const float*)d_in[7];
  float* out = (float*)d_out;

  float* ws    = (float*)d_ws;
  float* sums1 = ws;                    // 256
  float* sums2 = ws + 256;              // 256
  short* Wa    = (short*)(ws + 512);    // 72*8192 bf16

  pre_kernel<<<2305, 256, 0, stream>>>(W, Wa, sums1);
  conv_mfma<<<dim3(NPTS / BN, BB), 256, 0, stream>>>(x, coords, rot, dist, Wa, bias, out, sums1, sums2);
  bn_apply<<<BB * COUT, 256, 0, stream>>>(out, sums1, sums2, gamma, beta);
}

// Round 6
// 309.725 us; speedup vs baseline: 1.0107x; 1.0107x over previous
//
#include <hip/hip_runtime.h>

#define KTAPS 9
#define DIL 6
#define BN_EPS 1e-5f
#define BB 8
#define CIN 256
#define COUT 256
#define NPTS 8192
#define BN 64
#define XOFF 32      // window col 0 = n0 - XOFF; 128 window cols
#define BSTRIDE 40   // B row stride in shorts (80 B; 16B-aligned granules)

typedef __attribute__((ext_vector_type(8))) short short8;
typedef __attribute__((ext_vector_type(4))) float f32x4;

__device__ __forceinline__ unsigned short f2bf(float f) {
  union { float f; unsigned u; } v; v.f = f;
  unsigned r = v.u + 0x7fffu + ((v.u >> 16) & 1u);   // RNE
  return (unsigned short)(r >> 16);
}

__device__ __forceinline__ void async16(const void* gp, void* lp) {
  __builtin_amdgcn_global_load_lds(
      (const __attribute__((address_space(1))) unsigned int*)gp,
      (__attribute__((address_space(3))) unsigned int*)lp, 16, 0, 0);
}

// ---------------------------------------------------------------- pre: pack W + zero sums
// Wa[chunk][mi][kk]; chunk = ktap*8 + c8; element = W[mi][c8*32+kk][ktap]
__global__ __launch_bounds__(256)
void pre_kernel(const float* __restrict__ W, short* __restrict__ Wa,
                float* __restrict__ sums) {
  int bid = blockIdx.x;
  if (bid < 2304) {
    int idx = bid * 256 + threadIdx.x;
    int kk = idx & 31;
    int mi = (idx >> 5) & 255;
    int chunk = idx >> 13;
    int ktap = chunk >> 3;
    int c = ((chunk & 7) << 5) + kk;
    Wa[idx] = (short)f2bf(W[(size_t)mi * (CIN * KTAPS) + c * KTAPS + ktap]);
  } else {
    if (threadIdx.x < 512) sums[threadIdx.x] = 0.f;
  }
}

// ---------------------------------------------------------------- MFMA conv — fat triad regions
// 3 taps per region, 24 regions per block (vs 72 thin taps). Per region:
// issue 12 A-loads (L2) + 27 LDS build-reads + 12 B-frag reads together,
// 48 MFMAs per wave. Build(next triad) overlaps MFMA(current triad) via
// B triad double-buffer. x window DMA'd (R5-proven). lgkm-only barriers;
// one vmcnt barrier per c8.
__global__ __launch_bounds__(256, 2)
void conv_mfma(const float* __restrict__ x, const float* __restrict__ coords,
               const float* __restrict__ rot, const float* __restrict__ dist,
               const short* __restrict__ Wa, const float* __restrict__ bias,
               float* __restrict__ out,
               float* __restrict__ sums1, float* __restrict__ sums2) {
  __shared__ float x_win[2][4][32][32];       // 32 KB  x window dbuf, chunked
  __shared__ short Bt[2][3][BN][BSTRIDE];     // 30 KB  B triad dbuf (swizzled granules)
  __shared__ float g_lds[KTAPS][BN];          // 2.25 KB tap weights

  const int tid = threadIdx.x;
  const int b = blockIdx.y;
  const int n0 = blockIdx.x * BN;
  const int wave = tid >> 6;
  const int lane = tid & 63;
  const int col = lane & 15;
  const int quad = lane >> 4;

  // ---- tap weights -> g_lds (wave w covers taps w, w+4, w+8 for point lane)
  {
    const float* cb = coords + (size_t)b * 3 * NPTS;
    const float* rb = rot + (size_t)b * 3 * NPTS;
    const float* db = dist + (size_t)b * NPTS;
    const int n = n0 + lane;
    float c0x = cb[n], c0y = cb[NPTS + n], c0z = cb[2 * NPTS + n];
    float r0x = rb[n], r0y = rb[NPTS + n], r0z = rb[2 * NPTS + n];
    float d0 = db[n];
    float r0n = r0x * r0x + r0y * r0y + r0z * r0z;
    for (int k = wave; k < KTAPS; k += 4) {
      int j = n + (k - KTAPS / 2) * DIL;
      float gv = 0.f;
      if (j >= 0 && j < NPTS) {
        float dcx = c0x - cb[j], dcy = c0y - cb[NPTS + j], dcz = c0z - cb[2 * NPTS + j];
        float dc = dcx * dcx + dcy * dcy + dcz * dcz;
        float dd = d0 - db[j];
        dd *= dd;
        float gauss = expf(-(dc + dd) * 0.5f);
        float rjx = rb[j], rjy = rb[NPTS + j], rjz = rb[2 * NPTS + j];
        float num = r0x * rjx + r0y * rjy + r0z * rjz;
        float den = sqrtf(r0n * (rjx * rjx + rjy * rjy + rjz * rjz)) + 1e-8f;
        gv = gauss * fabsf(num / den);
      }
      g_lds[k][lane] = gv;
    }
  }

  const float* xb = x + (size_t)b * CIN * NPTS;
  const int arow0 = (wave * 64 + col) * 32 + quad * 8;  // short offset in a Wa chunk
  // B write addr (shorts): row = lane, granule = wave, 16B-granule XOR swizzle
  const int wrB = lane * BSTRIDE + ((wave ^ ((lane >> 3) & 3)) << 3);

  short8 af0[4], af1[4], af2[4];    // A fragments for the region's 3 taps

#define LOADAF(AF, CHUNK)                                               \
  {                                                                     \
    const short* p_ = Wa + (size_t)(CHUNK) * 8192 + arow0;              \
    _Pragma("unroll")                                                   \
    for (int m = 0; m < 4; ++m) AF[m] = *(const short8*)(p_ + m * 512); \
  }

  // DMA x window for channel-octet C8N into buf (C8N)&1 (R5-proven)
#define STAGE_DMA(C8N)                                                  \
  {                                                                     \
    const int buf_ = (C8N)&1;                                           \
    const int ch_ = wave * 8 + (lane >> 3);                             \
    const float* gr_ = xb + (size_t)((C8N)*32 + ch_) * NPTS;            \
    const int cg_ = (lane & 7) * 4;                                     \
    _Pragma("unroll")                                                   \
    for (int q_ = 0; q_ < 4; ++q_) {                                    \
      int jg_ = n0 - XOFF + q_ * 32 + cg_;                              \
      jg_ = jg_ < 0 ? 0 : (jg_ > NPTS - 4 ? NPTS - 4 : jg_);            \
      async16(gr_ + jg_, (float*)&x_win[buf_][q_][wave * 8][0] + lane * 4); \
    }                                                                   \
  }

  // build B for tap K into slice S of Bt[PP] from x buf XC
#define BUILDT(K, S, PP, XC)                                            \
  {                                                                     \
    float g_ = g_lds[K][lane];                                          \
    const int w_ = lane + ((K)-KTAPS / 2) * DIL + XOFF;                 \
    const float* xp_ = &x_win[XC][0][0][0] + ((w_ >> 5) << 10) + (w_ & 31) + wave * 256; \
    short8 p_;                                                          \
    _Pragma("unroll")                                                   \
    for (int cc = 0; cc < 8; ++cc)                                      \
      p_[cc] = (short)f2bf(xp_[cc * 32] * g_);                          \
    *(short8*)(&Bt[PP][S][0][0] + wrB) = p_;                            \
  }

  // MFMA one tap from slice S of Bt[PP] with A fragments AF
#define MFMAT(S, PP, AF)                                                \
  {                                                                     \
    const short* bb_ = &Bt[PP][S][0][0];                                \
    _Pragma("unroll")                                                   \
    for (int j = 0; j < 4; ++j) {                                       \
      short8 bfv_ = *(const short8*)(bb_ + (j * 16 + col) * BSTRIDE +   \
                                     ((quad ^ ((2 * j + (col >> 3)) & 3)) << 3)); \
      _Pragma("unroll")                                                 \
      for (int m = 0; m < 4; ++m)                                       \
        acc[m][j] = __builtin_amdgcn_mfma_f32_16x16x32_bf16(AF[m], bfv_, acc[m][j], 0, 0, 0); \
    }                                                                   \
  }

// pure-LDS barrier: no vmcnt drain (DMA stays in flight)
#define BAR()                                                           \
  {                                                                     \
    asm volatile("s_waitcnt lgkmcnt(0)" ::: "memory");                  \
    __builtin_amdgcn_s_barrier();                                       \
    __builtin_amdgcn_sched_barrier(0);                                  \
  }

// full barrier: drains DMA so all waves may read the new x buffer
#define BARFULL()                                                       \
  {                                                                     \
    asm volatile("s_waitcnt vmcnt(0) lgkmcnt(0)" ::: "memory");         \
    __builtin_amdgcn_s_barrier();                                       \
    __builtin_amdgcn_sched_barrier(0);                                  \
  }

  // region r in {0,1}: MFMA taps 3r..3r+2 from Bt[P], build taps 3r+3..3r+5 -> Bt[P^1]
#define REGION01(C8, R, P, DN)                                          \
  {                                                                     \
    LOADAF(af0, (3 * (R) + 0) * 8 + (C8));                              \
    LOADAF(af1, (3 * (R) + 1) * 8 + (C8));                              \
    LOADAF(af2, (3 * (R) + 2) * 8 + (C8));                              \
    if (DN) STAGE_DMA((C8) + 1);                                        \
    BUILDT(3 * (R) + 3, 0, (P) ^ 1, (C8)&1);                            \
    BUILDT(3 * (R) + 4, 1, (P) ^ 1, (C8)&1);                            \
    BUILDT(3 * (R) + 5, 2, (P) ^ 1, (C8)&1);                            \
    MFMAT(0, (P), af0);                                                 \
    MFMAT(1, (P), af1);                                                 \
    MFMAT(2, (P), af2);                                                 \
    BAR();                                                              \
  }

  // region 2: MFMA taps 6..8; publish next x buf; build next-c8 taps 0..2
#define REGION2(C8, P, DN)                                              \
  {                                                                     \
    LOADAF(af0, 48 + (C8));                                             \
    LOADAF(af1, 56 + (C8));                                             \
    LOADAF(af2, 64 + (C8));                                             \
    MFMAT(0, (P), af0);                                                 \
    MFMAT(1, (P), af1);                                                 \
    if (DN) {                                                           \
      BARFULL();                                                        \
      BUILDT(0, 0, (P) ^ 1, ((C8) + 1) & 1);                            \
      BUILDT(1, 1, (P) ^ 1, ((C8) + 1) & 1);                            \
      BUILDT(2, 2, (P) ^ 1, ((C8) + 1) & 1);                            \
      MFMAT(2, (P), af2);                                               \
      BAR();                                                            \
    } else {                                                            \
      MFMAT(2, (P), af2);                                               \
    }                                                                   \
  }

  f32x4 acc[4][4];
#pragma unroll
  for (int m = 0; m < 4; ++m)
#pragma unroll
    for (int j = 0; j < 4; ++j) acc[m][j] = (f32x4)0.f;

  // ---- prologue: DMA x_win[0], publish, build triad 0 (taps 0..2) into Bt[0]
  STAGE_DMA(0);
  asm volatile("s_waitcnt vmcnt(0)" ::: "memory");
  __syncthreads();          // x_win[0] + g_lds published
  BUILDT(0, 0, 0, 0);
  BUILDT(1, 1, 0, 0);
  BUILDT(2, 2, 0, 0);
  __syncthreads();          // Bt[0] triad published

#pragma unroll 1
  for (int c8 = 0; c8 < 8; ++c8) {
    const int P0 = c8 & 1;
    const bool dn = (c8 < 7);
    REGION01(c8, 0, P0, dn);
    REGION01(c8, 1, P0 ^ 1, false);
    REGION2(c8, P0, dn);
  }

  // ---- epilogue: bias, BN partial sums, store
  const int obase = wave * 64;
  float* outp = out + (size_t)b * COUT * NPTS + n0;
#pragma unroll
  for (int m = 0; m < 4; ++m) {
    const int o0 = obase + m * 16 + quad * 4;
    const float4 bv = *(const float4*)&bias[o0];
#pragma unroll
    for (int j = 0; j < 4; ++j) {
      acc[m][j][0] += bv.x; acc[m][j][1] += bv.y;
      acc[m][j][2] += bv.z; acc[m][j][3] += bv.w;
    }
#pragma unroll
    for (int r = 0; r < 4; ++r) {
      float s1 = 0.f, s2 = 0.f;
#pragma unroll
      for (int j = 0; j < 4; ++j) {
        float v = acc[m][j][r];
        s1 += v; s2 += v * v;
      }
      s1 += __shfl_xor(s1, 1); s2 += __shfl_xor(s2, 1);
      s1 += __shfl_xor(s1, 2); s2 += __shfl_xor(s2, 2);
      s1 += __shfl_xor(s1, 4); s2 += __shfl_xor(s2, 4);
      s1 += __shfl_xor(s1, 8); s2 += __shfl_xor(s2, 8);
      if (col == 0) {
        atomicAdd(&sums1[o0 + r], s1);
        atomicAdd(&sums2[o0 + r], s2);
      }
#pragma unroll
      for (int j = 0; j < 4; ++j)
        outp[(size_t)(o0 + r) * NPTS + j * 16 + col] = acc[m][j][r];
    }
  }
}

// ---------------------------------------------------------------- BN + ReLU
__global__ __launch_bounds__(256)
void bn_apply(float* __restrict__ out, const float* __restrict__ sums1,
              const float* __restrict__ sums2, const float* __restrict__ gamma,
              const float* __restrict__ beta) {
  int bo = blockIdx.x;
  int o = bo & (COUT - 1);
  const float inv = 1.f / (float)(BB * NPTS);
  float mean = sums1[o] * inv;
  float var = sums2[o] * inv - mean * mean;
  float scale = gamma[o] * rsqrtf(var + BN_EPS);
  float shift = beta[o] - mean * scale;
  float4* p = (float4*)(out + (size_t)bo * NPTS);
  for (int i = threadIdx.x; i < NPTS / 4; i += blockDim.x) {
    float4 v = p[i];
    v.x = fmaxf(fmaf(v.x, scale, shift), 0.f);
    v.y = fmaxf(fmaf(v.y, scale, shift), 0.f);
    v.z = fmaxf(fmaf(v.z, scale, shift), 0.f);
    v.w = fmaxf(fmaf(v.w, scale, shift), 0.f);
    p[i] = v;
  }
}

// ---------------------------------------------------------------- launch
extern "C" void kernel_launch(void* const* d_in, const int* in_sizes, int n_in,
                              void* d_out, int out_size, void* d_ws, size_t ws_size,
                              hipStream_t stream) {
  const float* x      = (const float*)d_in[0];
  const float* coords = (const float*)d_in[1];
  const float* rot    = (const float*)d_in[2];
  const float* dist   = (const float*)d_in[3];
  const float* W      = (const float*)d_in[4];
  const float* bias   = (const float*)d_in[5];
  const float* gamma  = (const float*)d_in[6];
  const float* beta   = (const float*)d_in[7];
  float* out = (float*)d_out;

  float* ws    = (float*)d_ws;
  float* sums1 = ws;                    // 256
  float* sums2 = ws + 256;              // 256
  short* Wa    = (short*)(ws + 512);    // 72*8192 bf16

  pre_kernel<<<2305, 256, 0, stream>>>(W, Wa, sums1);
  conv_mfma<<<dim3(NPTS / BN, BB), 256, 0, stream>>>(x, coords, rot, dist, Wa, bias, out, sums1, sums2);
  bn_apply<<<BB * COUT, 256, 0, stream>>>(out, sums1, sums2, gamma, beta);
}